// Round 10
// baseline (349.355 us; speedup 1.0000x reference)
//
#include <hip/hip_runtime.h>
#include <hip/hip_bf16.h>

#define D_MODEL 1024
#define N_HEADS 16
#define DK 64
#define B_SZ 4
#define T_SEQ 2048
#define M_ROWS (B_SZ * T_SEQ)   // 8192
#define QK_SCALE_LOG2 0.18033688f   // 0.125 * log2(e), folded into W_qkv Q-rows

typedef short bf16x8 __attribute__((ext_vector_type(8)));
typedef float f32x4  __attribute__((ext_vector_type(4)));

__device__ inline unsigned short f32_to_bf16(float f) {
    union { float f; unsigned int u; } v; v.f = f;
    unsigned int r = v.u + 0x7fff + ((v.u >> 16) & 1);   // RNE
    return (unsigned short)(r >> 16);
}
__device__ inline float bf16_to_f32(unsigned short h) {
    union { unsigned int u; float f; } v; v.u = ((unsigned int)h) << 16;
    return v.f;
}
__device__ inline unsigned int pack_bf16x2(float a, float b) {
    __hip_bfloat162 t = __float22bfloat162_rn(make_float2(a, b));
    union { __hip_bfloat162 v; unsigned int u; } c; c.v = t;
    return c.u;   // low 16 = a
}

// ---------------------------------------------------------------------------
// Cast fp32 -> bf16 (RNE); first nscaled elements multiplied by s.
// ---------------------------------------------------------------------------
__global__ __launch_bounds__(256) void cast_bf16(
    const float* __restrict__ src, unsigned short* __restrict__ dst,
    int n, int nscaled, float s)
{
    for (int i = (blockIdx.x * 256 + threadIdx.x) * 4; i < n;
         i += gridDim.x * 256 * 4) {
        float4 v = *(const float4*)(src + i);
        const float sc = (i < nscaled) ? s : 1.0f;
        ushort4 h;
        h.x = f32_to_bf16(v.x * sc); h.y = f32_to_bf16(v.y * sc);
        h.z = f32_to_bf16(v.z * sc); h.w = f32_to_bf16(v.w * sc);
        *(ushort4*)(dst + i) = h;
    }
}

// ---------------------------------------------------------------------------
// Split fp32 -> (hi, lo) bf16 planes (proj weights only).
// ---------------------------------------------------------------------------
__global__ __launch_bounds__(256) void split_bf16(
    const float* __restrict__ src, unsigned short* __restrict__ hi,
    unsigned short* __restrict__ lo, int n)
{
    for (int i = (blockIdx.x * 256 + threadIdx.x) * 4; i < n;
         i += gridDim.x * 256 * 4) {
        float4 v = *(const float4*)(src + i);
        ushort4 h, l;
        h.x = f32_to_bf16(v.x); l.x = f32_to_bf16(v.x - bf16_to_f32(h.x));
        h.y = f32_to_bf16(v.y); l.y = f32_to_bf16(v.y - bf16_to_f32(h.y));
        h.z = f32_to_bf16(v.z); l.z = f32_to_bf16(v.z - bf16_to_f32(h.z));
        h.w = f32_to_bf16(v.w); l.w = f32_to_bf16(v.w - bf16_to_f32(h.w));
        *(ushort4*)(hi + i) = h;
        *(ushort4*)(lo + i) = l;
    }
}

// ---------------------------------------------------------------------------
// Plain bf16 NT GEMM (unchanged).
// ---------------------------------------------------------------------------
__global__ __launch_bounds__(256) void gemm_bf16_nt(
    const unsigned short* __restrict__ A, const unsigned short* __restrict__ B,
    unsigned short* __restrict__ C, int M, int N, int K)
{
    __shared__ __align__(16) unsigned short sA[128 * 32];
    __shared__ __align__(16) unsigned short sB[128 * 32];

    const int t    = threadIdx.x;
    const int wave = t >> 6;
    const int lane = t & 63;
    const int l15  = lane & 15;
    const int quad = lane >> 4;
    const int m0   = blockIdx.y * 128;
    const int n0   = blockIdx.x * 128;

    const unsigned short* gplane = (wave < 2) ? A : B;
    unsigned short* lplane = (wave < 2) ? sA : sB;
    const int row0 = ((wave < 2) ? m0 : n0) + (wave & 1) * 64;
    const int lds0 = (wave & 1) * 2048;
    const unsigned short* gbase =
        gplane + (size_t)(row0 + (lane >> 2)) * K + (lane & 3) * 8;

    f32x4 acc[4][4];
#pragma unroll
    for (int i = 0; i < 4; ++i)
#pragma unroll
        for (int j = 0; j < 4; ++j) acc[i][j] = (f32x4){0.f, 0.f, 0.f, 0.f};

    const int wr = (wave >> 1) * 64;
    const int wc = (wave & 1) * 64;

    for (int k0 = 0; k0 < K; k0 += 32) {
#pragma unroll
        for (int i = 0; i < 4; ++i) {
            __builtin_amdgcn_global_load_lds(
                (const __attribute__((address_space(1))) unsigned int*)
                    (gbase + k0 + (size_t)i * 16 * K),
                (__attribute__((address_space(3))) unsigned int*)
                    (lplane + lds0 + i * 512),
                16, 0, 0);
        }
        __syncthreads();

        bf16x8 a[4], b[4];
#pragma unroll
        for (int f = 0; f < 4; ++f) {
            a[f] = *(const bf16x8*)&sA[(wr + f * 16 + l15) * 32 + quad * 8];
            b[f] = *(const bf16x8*)&sB[(wc + f * 16 + l15) * 32 + quad * 8];
        }
#pragma unroll
        for (int mi = 0; mi < 4; ++mi)
#pragma unroll
            for (int ni = 0; ni < 4; ++ni)
                acc[mi][ni] = __builtin_amdgcn_mfma_f32_16x16x32_bf16(
                    a[mi], b[ni], acc[mi][ni], 0, 0, 0);
        __syncthreads();
    }

#pragma unroll
    for (int mi = 0; mi < 4; ++mi)
#pragma unroll
        for (int r = 0; r < 4; ++r) {
            unsigned short* crow =
                C + (size_t)(m0 + wr + mi * 16 + quad * 4 + r) * N + n0 + wc + l15;
#pragma unroll
            for (int ni = 0; ni < 4; ++ni)
                crow[ni * 16] = f32_to_bf16(acc[mi][ni][r]);
        }
}

// ---------------------------------------------------------------------------
// Split-bf16 NT GEMM (proj only, unchanged): 3 MFMAs per frag pair.
// ---------------------------------------------------------------------------
__global__ __launch_bounds__(256) void gemm_split_nt(
    const unsigned short* __restrict__ Ah, const unsigned short* __restrict__ Al,
    const unsigned short* __restrict__ Bh, const unsigned short* __restrict__ Bl,
    float* __restrict__ C, int M, int N, int K)
{
    __shared__ __align__(16) unsigned short sA_h[128 * 32];
    __shared__ __align__(16) unsigned short sA_l[128 * 32];
    __shared__ __align__(16) unsigned short sB_h[128 * 32];
    __shared__ __align__(16) unsigned short sB_l[128 * 32];

    const int t    = threadIdx.x;
    const int wave = t >> 6;
    const int lane = t & 63;
    const int l15  = lane & 15;
    const int quad = lane >> 4;
    const int m0   = blockIdx.y * 128;
    const int n0   = blockIdx.x * 128;

    const unsigned short* gplane = wave == 0 ? Ah : wave == 1 ? Al
                                 : wave == 2 ? Bh : Bl;
    unsigned short* lplane = wave == 0 ? sA_h : wave == 1 ? sA_l
                           : wave == 2 ? sB_h : sB_l;
    const int row0 = (wave < 2) ? m0 : n0;
    const unsigned short* gbase =
        gplane + (size_t)(row0 + (lane >> 2)) * K + (lane & 3) * 8;

    f32x4 acc[4][4];
#pragma unroll
    for (int i = 0; i < 4; ++i)
#pragma unroll
        for (int j = 0; j < 4; ++j) acc[i][j] = (f32x4){0.f, 0.f, 0.f, 0.f};

    const int wr = (wave >> 1) * 64;
    const int wc = (wave & 1) * 64;

    for (int k0 = 0; k0 < K; k0 += 32) {
#pragma unroll
        for (int i = 0; i < 8; ++i) {
            __builtin_amdgcn_global_load_lds(
                (const __attribute__((address_space(1))) unsigned int*)
                    (gbase + k0 + (size_t)i * 16 * K),
                (__attribute__((address_space(3))) unsigned int*)
                    (lplane + i * 512),
                16, 0, 0);
        }
        __syncthreads();

        bf16x8 a_h[4], a_l[4], b_h[4], b_l[4];
#pragma unroll
        for (int f = 0; f < 4; ++f) {
            const int ar = wr + f * 16 + l15;
            a_h[f] = *(const bf16x8*)&sA_h[ar * 32 + quad * 8];
            a_l[f] = *(const bf16x8*)&sA_l[ar * 32 + quad * 8];
            const int br = wc + f * 16 + l15;
            b_h[f] = *(const bf16x8*)&sB_h[br * 32 + quad * 8];
            b_l[f] = *(const bf16x8*)&sB_l[br * 32 + quad * 8];
        }
#pragma unroll
        for (int mi = 0; mi < 4; ++mi)
#pragma unroll
            for (int ni = 0; ni < 4; ++ni) {
                acc[mi][ni] = __builtin_amdgcn_mfma_f32_16x16x32_bf16(
                    a_h[mi], b_h[ni], acc[mi][ni], 0, 0, 0);
                acc[mi][ni] = __builtin_amdgcn_mfma_f32_16x16x32_bf16(
                    a_h[mi], b_l[ni], acc[mi][ni], 0, 0, 0);
                acc[mi][ni] = __builtin_amdgcn_mfma_f32_16x16x32_bf16(
                    a_l[mi], b_h[ni], acc[mi][ni], 0, 0, 0);
            }
        __syncthreads();
    }

#pragma unroll
    for (int mi = 0; mi < 4; ++mi)
#pragma unroll
        for (int r = 0; r < 4; ++r) {
            float* crow = C + (size_t)(m0 + wr + mi * 16 + quad * 4 + r) * N
                          + n0 + wc + l15;
#pragma unroll
            for (int ni = 0; ni < 4; ++ni)
                crow[ni * 16] = acc[mi][ni][r];
        }
}

// ---------------------------------------------------------------------------
// Build V^T per (b,h) with PV kv-permutation baked in (unchanged):
// vt[b,h,dk,pos], pos = (kv&~31) | quad(kv)<<3 | s(kv)<<2 | r(kv).
// ---------------------------------------------------------------------------
__global__ __launch_bounds__(256) void prep_vt(
    const unsigned short* __restrict__ qkvb, unsigned short* __restrict__ vt)
{
    __shared__ unsigned short VT_s[64][264];
    const int t  = threadIdx.x;
    const int b  = blockIdx.z, h = blockIdx.y;
    const int t0 = blockIdx.x * 256;
    const unsigned short* vb = qkvb + (size_t)(b * T_SEQ) * (3 * D_MODEL)
                               + 2 * D_MODEL + h * DK;
#pragma unroll
    for (int it = 0; it < 16; ++it) {
        const int trow = (t >> 4) + it * 16;
        const int dk0  = (t & 15) * 4;
        ushort4 v = *(const ushort4*)(vb + (size_t)(t0 + trow) * (3 * D_MODEL) + dk0);
        VT_s[dk0 + 0][trow] = v.x; VT_s[dk0 + 1][trow] = v.y;
        VT_s[dk0 + 2][trow] = v.z; VT_s[dk0 + 3][trow] = v.w;
    }
    __syncthreads();
    const int row = t >> 2;
    const int c0w = (t & 3) * 64;
    unsigned short* dst = vt + ((size_t)(b * N_HEADS + h) * DK + row) * T_SEQ + t0 + c0w;
#pragma unroll
    for (int i = 0; i < 8; ++i) {
        const int lp8   = c0w + i * 8;
        const int sbase = (lp8 & ~31) + ((lp8 >> 3) & 3) * 4;
        ushort4 a  = *(const ushort4*)&VT_s[row][sbase];        // s=0
        ushort4 b4 = *(const ushort4*)&VT_s[row][sbase + 16];   // s=1
        union { ushort4 p[2]; uint4 v; } pk;
        pk.p[0] = a; pk.p[1] = b4;
        *(uint4*)(dst + i * 8) = pk.v;
    }
}

// ---------------------------------------------------------------------------
// MFMA flash attention, R10: 256 q/block (64 q/wave, 4 subtiles of 16).
// Same full-rate paired PV as R9, but each K/V LDS read now serves 2x the
// MFMA work (4 q-subtiles share K-frags; V-frags shared across all qs).
// S computed per 32-kv group (gl) to cap live S registers at 8 f32x4.
// ---------------------------------------------------------------------------
__global__ __launch_bounds__(256) void attn_mfma(
    const unsigned short* __restrict__ qkvb,   // [B,T,3D] bf16 (Q pre-scaled)
    const unsigned short* __restrict__ vt,     // [B,H,DK,T] bf16, kv-permuted
    unsigned short* __restrict__ ohi,          // [B,T,D] bf16 hi
    unsigned short* __restrict__ olo)          // [B,T,D] bf16 lo
{
    __shared__ __align__(16) unsigned short Ksw[128 * 64];   // [kv][dk] swizzled
    __shared__ __align__(16) unsigned short Vsw[64 * 128];   // [dk][pos] swizzled

    const int t    = threadIdx.x;
    const int wave = t >> 6;
    const int lane = t & 63;
    const int l15  = t & 15;
    const int quad = lane >> 4;
    const int swz  = l15 & 7;

    const int b  = blockIdx.z;
    const int h  = blockIdx.y;
    const int q0 = blockIdx.x * 256;

    // Q fragments (loop-invariant): 4 q-subtiles x 2 dk-chunks
    bf16x8 qa[4][2];
#pragma unroll
    for (int qs = 0; qs < 4; ++qs) {
        const unsigned short* qrow =
            qkvb + ((size_t)(b * T_SEQ) + q0 + wave * 64 + qs * 16 + l15)
                   * (3 * D_MODEL) + h * DK;
        qa[qs][0] = *(const bf16x8*)(qrow + quad * 8);
        qa[qs][1] = *(const bf16x8*)(qrow + 32 + quad * 8);
    }

    f32x4 O[4][4], Lacc[4];
#pragma unroll
    for (int qs = 0; qs < 4; ++qs) {
        Lacc[qs] = (f32x4){0.f, 0.f, 0.f, 0.f};
#pragma unroll
        for (int nd = 0; nd < 4; ++nd) O[qs][nd] = (f32x4){0.f, 0.f, 0.f, 0.f};
    }

    const short one_bf = (short)0x3F80;
    const bf16x8 ones8 = {one_bf, one_bf, one_bf, one_bf,
                          one_bf, one_bf, one_bf, one_bf};

    const unsigned short* kbase =
        qkvb + (size_t)(b * T_SEQ) * (3 * D_MODEL) + D_MODEL + h * DK;
    const unsigned short* vbase = vt + (size_t)(b * N_HEADS + h) * DK * T_SEQ;

    for (int c0 = 0; c0 < T_SEQ; c0 += 128) {
        // stage K [128 kv][64 dk] + permuted V^T [64 dk][128 pos], swizzled
        int f = t;
#pragma unroll
        for (int it = 0; it < 4; ++it, f += 256) {
            const int kr = f >> 3, kc = f & 7;
            *(uint4*)&Ksw[kr * 64 + ((kc ^ (kr & 7)) * 8)] =
                *(const uint4*)(kbase + (size_t)(c0 + kr) * (3 * D_MODEL) + kc * 8);
            const int vr = f >> 4, vc = f & 15;
            *(uint4*)&Vsw[vr * 128 + ((((vc & 7) ^ (vr & 7)) | (vc & 8)) * 8)] =
                *(const uint4*)(vbase + (size_t)vr * T_SEQ + c0 + vc * 8);
        }
        __syncthreads();

#pragma unroll
        for (int half = 0; half < 2; ++half) {
#pragma unroll
            for (int gl = 0; gl < 2; ++gl) {
                // S^T = K * Q^T for this 32-kv group (nf = 2gl, 2gl+1)
                f32x4 S[4][2];
#pragma unroll
                for (int qs = 0; qs < 4; ++qs) {
                    S[qs][0] = (f32x4){0.f, 0.f, 0.f, 0.f};
                    S[qs][1] = (f32x4){0.f, 0.f, 0.f, 0.f};
                }
#pragma unroll
                for (int ks = 0; ks < 2; ++ks) {
                    const int ch = ks * 4 + quad;
#pragma unroll
                    for (int jj = 0; jj < 2; ++jj) {
                        const int row = half * 64 + (gl * 2 + jj) * 16 + l15; // kv
                        const bf16x8 kf =
                            *(const bf16x8*)&Ksw[row * 64 + ((ch ^ swz) * 8)];
#pragma unroll
                        for (int qs = 0; qs < 4; ++qs)
                            S[qs][jj] = __builtin_amdgcn_mfma_f32_16x16x32_bf16(
                                kf, qa[qs][ks], S[qs][jj], 0, 0, 0);
                    }
                }

                // exp -> paired P frags -> PV + L (full-rate, V shared over qs)
                bf16x8 pf[4];
#pragma unroll
                for (int qs = 0; qs < 4; ++qs) {
                    union { uint4 u; bf16x8 v; } cv;
                    const f32x4 s0 = S[qs][0];
                    const f32x4 s1 = S[qs][1];
                    cv.u.x = pack_bf16x2(__builtin_amdgcn_exp2f(s0[0]),
                                         __builtin_amdgcn_exp2f(s0[1]));
                    cv.u.y = pack_bf16x2(__builtin_amdgcn_exp2f(s0[2]),
                                         __builtin_amdgcn_exp2f(s0[3]));
                    cv.u.z = pack_bf16x2(__builtin_amdgcn_exp2f(s1[0]),
                                         __builtin_amdgcn_exp2f(s1[1]));
                    cv.u.w = pack_bf16x2(__builtin_amdgcn_exp2f(s1[2]),
                                         __builtin_amdgcn_exp2f(s1[3]));
                    pf[qs] = cv.v;
                }
                const int g = half * 2 + gl;          // 32-kv group in tile
                const int c = g * 4 + quad;           // Vsw chunk index
                const int vo = (((c & 7) ^ swz) | (c & 8)) * 8;
#pragma unroll
                for (int nd = 0; nd < 4; ++nd) {
                    const bf16x8 vb =
                        *(const bf16x8*)&Vsw[(nd * 16 + l15) * 128 + vo];
#pragma unroll
                    for (int qs = 0; qs < 4; ++qs)
                        O[qs][nd] = __builtin_amdgcn_mfma_f32_16x16x32_bf16(
                            pf[qs], vb, O[qs][nd], 0, 0, 0);
                }
#pragma unroll
                for (int qs = 0; qs < 4; ++qs)
                    Lacc[qs] = __builtin_amdgcn_mfma_f32_16x16x32_bf16(
                        pf[qs], ones8, Lacc[qs], 0, 0, 0);
            }
        }
        __syncthreads();
    }

    // epilogue: rows q = q0 + wave*64 + qs*16 + quad*4 + r; cols h*64+nd*16+l15
#pragma unroll
    for (int qs = 0; qs < 4; ++qs)
#pragma unroll
        for (int r = 0; r < 4; ++r) {
            const float invl = 1.0f / Lacc[qs][r];
            const size_t rowbase =
                ((size_t)(b * T_SEQ) + q0 + wave * 64 + qs * 16 + quad * 4 + r)
                * D_MODEL + h * DK + l15;
#pragma unroll
            for (int nd = 0; nd < 4; ++nd) {
                const float v = O[qs][nd][r] * invl;
                const unsigned short hh = f32_to_bf16(v);
                ohi[rowbase + nd * 16] = hh;
                olo[rowbase + nd * 16] = f32_to_bf16(v - bf16_to_f32(hh));
            }
        }
}

// ---------------------------------------------------------------------------
extern "C" void kernel_launch(void* const* d_in, const int* in_sizes, int n_in,
                              void* d_out, int out_size, void* d_ws, size_t ws_size,
                              hipStream_t stream)
{
    const float* x      = (const float*)d_in[0];
    const float* W_qkv  = (const float*)d_in[1];
    const float* W_proj = (const float*)d_in[2];
    float* out = (float*)d_out;

    const size_t XN = (size_t)M_ROWS * D_MODEL;        // 8.4M
    const size_t WQ = (size_t)3 * D_MODEL * D_MODEL;   // 3.1M
    const size_t WP = (size_t)D_MODEL * D_MODEL;       // 1.0M
    unsigned short* xb   = (unsigned short*)d_ws;
    unsigned short* wqb  = xb + XN;
    unsigned short* wph  = wqb + WQ;
    unsigned short* wpl  = wph + WP;
    unsigned short* qkvb = wpl + WP;
    unsigned short* vtb  = qkvb + (size_t)M_ROWS * 3 * D_MODEL;
    unsigned short* alo  = vtb + (size_t)B_SZ * N_HEADS * DK * T_SEQ;
    unsigned short* ahi  = xb;   // overlay (x plane dead after QKV GEMM)

    dim3 blk(256);
    cast_bf16<<<512, blk, 0, stream>>>(x, xb, (int)XN, 0, 1.0f);
    cast_bf16<<<256, blk, 0, stream>>>(W_qkv, wqb, (int)WQ,
                                       D_MODEL * D_MODEL, QK_SCALE_LOG2);
    split_bf16<<<128, blk, 0, stream>>>(W_proj, wph, wpl, (int)WP);

    gemm_bf16_nt<<<dim3(3 * D_MODEL / 128, M_ROWS / 128), blk, 0, stream>>>(
        xb, wqb, qkvb, M_ROWS, 3 * D_MODEL, D_MODEL);

    prep_vt<<<dim3(T_SEQ / 256, N_HEADS, B_SZ), blk, 0, stream>>>(qkvb, vtb);
    attn_mfma<<<dim3(T_SEQ / 256, N_HEADS, B_SZ), blk, 0, stream>>>(
        qkvb, vtb, ahi, alo);

    gemm_split_nt<<<dim3(D_MODEL / 128, M_ROWS / 128), blk, 0, stream>>>(
        ahi, alo, wph, wpl, out, M_ROWS, D_MODEL, D_MODEL);
}

// Round 11
// 342.371 us; speedup vs baseline: 1.0204x; 1.0204x over previous
//
#include <hip/hip_runtime.h>
#include <hip/hip_bf16.h>

#define D_MODEL 1024
#define N_HEADS 16
#define DK 64
#define B_SZ 4
#define T_SEQ 2048
#define M_ROWS (B_SZ * T_SEQ)   // 8192
#define QK_SCALE_LOG2 0.18033688f   // 0.125 * log2(e), folded into W_qkv Q-rows

typedef short bf16x8 __attribute__((ext_vector_type(8)));
typedef float f32x4  __attribute__((ext_vector_type(4)));

__device__ inline unsigned short f32_to_bf16(float f) {
    union { float f; unsigned int u; } v; v.f = f;
    unsigned int r = v.u + 0x7fff + ((v.u >> 16) & 1);   // RNE
    return (unsigned short)(r >> 16);
}
__device__ inline float bf16_to_f32(unsigned short h) {
    union { unsigned int u; float f; } v; v.u = ((unsigned int)h) << 16;
    return v.f;
}
__device__ inline unsigned int pack_bf16x2(float a, float b) {
    __hip_bfloat162 t = __float22bfloat162_rn(make_float2(a, b));
    union { __hip_bfloat162 v; unsigned int u; } c; c.v = t;
    return c.u;   // low 16 = a
}

// ---------------------------------------------------------------------------
// Cast fp32 -> bf16 (RNE); first nscaled elements multiplied by s.
// ---------------------------------------------------------------------------
__global__ __launch_bounds__(256) void cast_bf16(
    const float* __restrict__ src, unsigned short* __restrict__ dst,
    int n, int nscaled, float s)
{
    for (int i = (blockIdx.x * 256 + threadIdx.x) * 4; i < n;
         i += gridDim.x * 256 * 4) {
        float4 v = *(const float4*)(src + i);
        const float sc = (i < nscaled) ? s : 1.0f;
        ushort4 h;
        h.x = f32_to_bf16(v.x * sc); h.y = f32_to_bf16(v.y * sc);
        h.z = f32_to_bf16(v.z * sc); h.w = f32_to_bf16(v.w * sc);
        *(ushort4*)(dst + i) = h;
    }
}

// ---------------------------------------------------------------------------
// Split fp32 -> (hi, lo) bf16 planes (proj weights only).
// ---------------------------------------------------------------------------
__global__ __launch_bounds__(256) void split_bf16(
    const float* __restrict__ src, unsigned short* __restrict__ hi,
    unsigned short* __restrict__ lo, int n)
{
    for (int i = (blockIdx.x * 256 + threadIdx.x) * 4; i < n;
         i += gridDim.x * 256 * 4) {
        float4 v = *(const float4*)(src + i);
        ushort4 h, l;
        h.x = f32_to_bf16(v.x); l.x = f32_to_bf16(v.x - bf16_to_f32(h.x));
        h.y = f32_to_bf16(v.y); l.y = f32_to_bf16(v.y - bf16_to_f32(h.y));
        h.z = f32_to_bf16(v.z); l.z = f32_to_bf16(v.z - bf16_to_f32(h.z));
        h.w = f32_to_bf16(v.w); l.w = f32_to_bf16(v.w - bf16_to_f32(h.w));
        *(ushort4*)(hi + i) = h;
        *(ushort4*)(lo + i) = l;
    }
}

// ---------------------------------------------------------------------------
// Plain bf16 NT GEMM (unchanged).
// ---------------------------------------------------------------------------
__global__ __launch_bounds__(256) void gemm_bf16_nt(
    const unsigned short* __restrict__ A, const unsigned short* __restrict__ B,
    unsigned short* __restrict__ C, int M, int N, int K)
{
    __shared__ __align__(16) unsigned short sA[128 * 32];
    __shared__ __align__(16) unsigned short sB[128 * 32];

    const int t    = threadIdx.x;
    const int wave = t >> 6;
    const int lane = t & 63;
    const int l15  = lane & 15;
    const int quad = lane >> 4;
    const int m0   = blockIdx.y * 128;
    const int n0   = blockIdx.x * 128;

    const unsigned short* gplane = (wave < 2) ? A : B;
    unsigned short* lplane = (wave < 2) ? sA : sB;
    const int row0 = ((wave < 2) ? m0 : n0) + (wave & 1) * 64;
    const int lds0 = (wave & 1) * 2048;
    const unsigned short* gbase =
        gplane + (size_t)(row0 + (lane >> 2)) * K + (lane & 3) * 8;

    f32x4 acc[4][4];
#pragma unroll
    for (int i = 0; i < 4; ++i)
#pragma unroll
        for (int j = 0; j < 4; ++j) acc[i][j] = (f32x4){0.f, 0.f, 0.f, 0.f};

    const int wr = (wave >> 1) * 64;
    const int wc = (wave & 1) * 64;

    for (int k0 = 0; k0 < K; k0 += 32) {
#pragma unroll
        for (int i = 0; i < 4; ++i) {
            __builtin_amdgcn_global_load_lds(
                (const __attribute__((address_space(1))) unsigned int*)
                    (gbase + k0 + (size_t)i * 16 * K),
                (__attribute__((address_space(3))) unsigned int*)
                    (lplane + lds0 + i * 512),
                16, 0, 0);
        }
        __syncthreads();

        bf16x8 a[4], b[4];
#pragma unroll
        for (int f = 0; f < 4; ++f) {
            a[f] = *(const bf16x8*)&sA[(wr + f * 16 + l15) * 32 + quad * 8];
            b[f] = *(const bf16x8*)&sB[(wc + f * 16 + l15) * 32 + quad * 8];
        }
#pragma unroll
        for (int mi = 0; mi < 4; ++mi)
#pragma unroll
            for (int ni = 0; ni < 4; ++ni)
                acc[mi][ni] = __builtin_amdgcn_mfma_f32_16x16x32_bf16(
                    a[mi], b[ni], acc[mi][ni], 0, 0, 0);
        __syncthreads();
    }

#pragma unroll
    for (int mi = 0; mi < 4; ++mi)
#pragma unroll
        for (int r = 0; r < 4; ++r) {
            unsigned short* crow =
                C + (size_t)(m0 + wr + mi * 16 + quad * 4 + r) * N + n0 + wc + l15;
#pragma unroll
            for (int ni = 0; ni < 4; ++ni)
                crow[ni * 16] = f32_to_bf16(acc[mi][ni][r]);
        }
}

// ---------------------------------------------------------------------------
// Split-bf16 NT GEMM (proj only, unchanged): 3 MFMAs per frag pair.
// ---------------------------------------------------------------------------
__global__ __launch_bounds__(256) void gemm_split_nt(
    const unsigned short* __restrict__ Ah, const unsigned short* __restrict__ Al,
    const unsigned short* __restrict__ Bh, const unsigned short* __restrict__ Bl,
    float* __restrict__ C, int M, int N, int K)
{
    __shared__ __align__(16) unsigned short sA_h[128 * 32];
    __shared__ __align__(16) unsigned short sA_l[128 * 32];
    __shared__ __align__(16) unsigned short sB_h[128 * 32];
    __shared__ __align__(16) unsigned short sB_l[128 * 32];

    const int t    = threadIdx.x;
    const int wave = t >> 6;
    const int lane = t & 63;
    const int l15  = lane & 15;
    const int quad = lane >> 4;
    const int m0   = blockIdx.y * 128;
    const int n0   = blockIdx.x * 128;

    const unsigned short* gplane = wave == 0 ? Ah : wave == 1 ? Al
                                 : wave == 2 ? Bh : Bl;
    unsigned short* lplane = wave == 0 ? sA_h : wave == 1 ? sA_l
                           : wave == 2 ? sB_h : sB_l;
    const int row0 = (wave < 2) ? m0 : n0;
    const unsigned short* gbase =
        gplane + (size_t)(row0 + (lane >> 2)) * K + (lane & 3) * 8;

    f32x4 acc[4][4];
#pragma unroll
    for (int i = 0; i < 4; ++i)
#pragma unroll
        for (int j = 0; j < 4; ++j) acc[i][j] = (f32x4){0.f, 0.f, 0.f, 0.f};

    const int wr = (wave >> 1) * 64;
    const int wc = (wave & 1) * 64;

    for (int k0 = 0; k0 < K; k0 += 32) {
#pragma unroll
        for (int i = 0; i < 8; ++i) {
            __builtin_amdgcn_global_load_lds(
                (const __attribute__((address_space(1))) unsigned int*)
                    (gbase + k0 + (size_t)i * 16 * K),
                (__attribute__((address_space(3))) unsigned int*)
                    (lplane + i * 512),
                16, 0, 0);
        }
        __syncthreads();

        bf16x8 a_h[4], a_l[4], b_h[4], b_l[4];
#pragma unroll
        for (int f = 0; f < 4; ++f) {
            const int ar = wr + f * 16 + l15;
            a_h[f] = *(const bf16x8*)&sA_h[ar * 32 + quad * 8];
            a_l[f] = *(const bf16x8*)&sA_l[ar * 32 + quad * 8];
            const int br = wc + f * 16 + l15;
            b_h[f] = *(const bf16x8*)&sB_h[br * 32 + quad * 8];
            b_l[f] = *(const bf16x8*)&sB_l[br * 32 + quad * 8];
        }
#pragma unroll
        for (int mi = 0; mi < 4; ++mi)
#pragma unroll
            for (int ni = 0; ni < 4; ++ni) {
                acc[mi][ni] = __builtin_amdgcn_mfma_f32_16x16x32_bf16(
                    a_h[mi], b_h[ni], acc[mi][ni], 0, 0, 0);
                acc[mi][ni] = __builtin_amdgcn_mfma_f32_16x16x32_bf16(
                    a_h[mi], b_l[ni], acc[mi][ni], 0, 0, 0);
                acc[mi][ni] = __builtin_amdgcn_mfma_f32_16x16x32_bf16(
                    a_l[mi], b_h[ni], acc[mi][ni], 0, 0, 0);
            }
        __syncthreads();
    }

#pragma unroll
    for (int mi = 0; mi < 4; ++mi)
#pragma unroll
        for (int r = 0; r < 4; ++r) {
            float* crow = C + (size_t)(m0 + wr + mi * 16 + quad * 4 + r) * N
                          + n0 + wc + l15;
#pragma unroll
            for (int ni = 0; ni < 4; ++ni)
                crow[ni * 16] = acc[mi][ni][r];
        }
}

// ---------------------------------------------------------------------------
// Build V^T per (b,h) with PV kv-permutation baked in (unchanged):
// vt[b,h,dk,pos], pos = (kv&~31) | quad(kv)<<3 | s(kv)<<2 | r(kv).
// ---------------------------------------------------------------------------
__global__ __launch_bounds__(256) void prep_vt(
    const unsigned short* __restrict__ qkvb, unsigned short* __restrict__ vt)
{
    __shared__ unsigned short VT_s[64][264];
    const int t  = threadIdx.x;
    const int b  = blockIdx.z, h = blockIdx.y;
    const int t0 = blockIdx.x * 256;
    const unsigned short* vb = qkvb + (size_t)(b * T_SEQ) * (3 * D_MODEL)
                               + 2 * D_MODEL + h * DK;
#pragma unroll
    for (int it = 0; it < 16; ++it) {
        const int trow = (t >> 4) + it * 16;
        const int dk0  = (t & 15) * 4;
        ushort4 v = *(const ushort4*)(vb + (size_t)(t0 + trow) * (3 * D_MODEL) + dk0);
        VT_s[dk0 + 0][trow] = v.x; VT_s[dk0 + 1][trow] = v.y;
        VT_s[dk0 + 2][trow] = v.z; VT_s[dk0 + 3][trow] = v.w;
    }
    __syncthreads();
    const int row = t >> 2;
    const int c0w = (t & 3) * 64;
    unsigned short* dst = vt + ((size_t)(b * N_HEADS + h) * DK + row) * T_SEQ + t0 + c0w;
#pragma unroll
    for (int i = 0; i < 8; ++i) {
        const int lp8   = c0w + i * 8;
        const int sbase = (lp8 & ~31) + ((lp8 >> 3) & 3) * 4;
        ushort4 a  = *(const ushort4*)&VT_s[row][sbase];        // s=0
        ushort4 b4 = *(const ushort4*)&VT_s[row][sbase + 16];   // s=1
        union { ushort4 p[2]; uint4 v; } pk;
        pk.p[0] = a; pk.p[1] = b4;
        *(uint4*)(dst + i * 8) = pk.v;
    }
}

// ---------------------------------------------------------------------------
// MFMA flash attention, R11 = R9 tile config (128 q/block, 32 q/wave) with
// double-buffered async staging. global_load_lds writes wave-uniform base +
// lane*16B; the XOR swizzle is applied on the SOURCE address (lane L fetches
// the chunk belonging at its LDS slot), keeping coalescing (permutation stays
// within a 128/256B segment). One barrier per tile: the compiler's vmcnt(0)
// before s_barrier waits exactly for tile i's loads, which were issued one
// full compute section earlier -> latency hidden.
// ---------------------------------------------------------------------------
__global__ __launch_bounds__(256) void attn_mfma(
    const unsigned short* __restrict__ qkvb,   // [B,T,3D] bf16 (Q pre-scaled)
    const unsigned short* __restrict__ vt,     // [B,H,DK,T] bf16, kv-permuted
    unsigned short* __restrict__ ohi,          // [B,T,D] bf16 hi
    unsigned short* __restrict__ olo)          // [B,T,D] bf16 lo
{
    __shared__ __align__(16) unsigned short Ksw[2][128 * 64];  // [kv][dk] swizzled
    __shared__ __align__(16) unsigned short Vsw[2][64 * 128];  // [dk][pos] swizzled

    const int t    = threadIdx.x;
    const int wave = t >> 6;
    const int lane = t & 63;
    const int l15  = t & 15;
    const int quad = lane >> 4;
    const int swz  = l15 & 7;

    const int b  = blockIdx.z;
    const int h  = blockIdx.y;
    const int q0 = blockIdx.x * 128;

    // Q fragments (loop-invariant): 2 q-subtiles x 2 dk-chunks
    bf16x8 qa[2][2];
#pragma unroll
    for (int qs = 0; qs < 2; ++qs) {
        const unsigned short* qrow =
            qkvb + ((size_t)(b * T_SEQ) + q0 + wave * 32 + qs * 16 + l15)
                   * (3 * D_MODEL) + h * DK;
        qa[qs][0] = *(const bf16x8*)(qrow + quad * 8);
        qa[qs][1] = *(const bf16x8*)(qrow + 32 + quad * 8);
    }

    f32x4 O[2][4], Lacc[2];
#pragma unroll
    for (int qs = 0; qs < 2; ++qs) {
        Lacc[qs] = (f32x4){0.f, 0.f, 0.f, 0.f};
#pragma unroll
        for (int nd = 0; nd < 4; ++nd) O[qs][nd] = (f32x4){0.f, 0.f, 0.f, 0.f};
    }

    const short one_bf = (short)0x3F80;
    const bf16x8 ones8 = {one_bf, one_bf, one_bf, one_bf,
                          one_bf, one_bf, one_bf, one_bf};

    const unsigned short* kbase =
        qkvb + (size_t)(b * T_SEQ) * (3 * D_MODEL) + D_MODEL + h * DK;
    const unsigned short* vbase = vt + (size_t)(b * N_HEADS + h) * DK * T_SEQ;

    // source-side swizzle (tile-invariant pieces):
    // K instr i: local row = wave*32 + i*8 + (lane>>3); chunk = (lane&7)^(lane>>3)
    const int krl  = wave * 32 + (lane >> 3);
    const int kcol = ((lane & 7) ^ (lane >> 3)) * 8;
    // V instr i: row = wave*16 + i*4 + (lane>>4); chunk = ((sw&7)^(row&7))|(sw&8)
    const int vrl = wave * 16 + (lane >> 4);
    const int vsw = lane & 15;

    // prologue: issue tile 0 loads into buffer 0
#pragma unroll
    for (int i = 0; i < 4; ++i) {
        const int rk = krl + i * 8;
        __builtin_amdgcn_global_load_lds(
            (const __attribute__((address_space(1))) unsigned int*)
                (kbase + (size_t)rk * (3 * D_MODEL) + kcol),
            (__attribute__((address_space(3))) unsigned int*)
                (&Ksw[0][(wave * 4 + i) * 512]),
            16, 0, 0);
        const int rv = vrl + i * 4;
        const int vc = (((vsw & 7) ^ (rv & 7)) | (vsw & 8)) * 8;
        __builtin_amdgcn_global_load_lds(
            (const __attribute__((address_space(1))) unsigned int*)
                (vbase + (size_t)rv * T_SEQ + vc),
            (__attribute__((address_space(3))) unsigned int*)
                (&Vsw[0][(wave * 4 + i) * 512]),
            16, 0, 0);
    }

    const int NT = T_SEQ / 128;
    for (int tile = 0; tile < NT; ++tile) {
        __syncthreads();   // vmcnt(0) drain: tile's loads (issued last iter) done;
                           // also fences compute of tile-1 before buf reuse.

        // issue next tile's loads into the other buffer (fly during compute)
        if (tile + 1 < NT) {
            const int c0n = (tile + 1) * 128;
            const int nb  = (tile + 1) & 1;
#pragma unroll
            for (int i = 0; i < 4; ++i) {
                const int rk = krl + i * 8;
                __builtin_amdgcn_global_load_lds(
                    (const __attribute__((address_space(1))) unsigned int*)
                        (kbase + (size_t)(c0n + rk) * (3 * D_MODEL) + kcol),
                    (__attribute__((address_space(3))) unsigned int*)
                        (&Ksw[nb][(wave * 4 + i) * 512]),
                    16, 0, 0);
                const int rv = vrl + i * 4;
                const int vc = (((vsw & 7) ^ (rv & 7)) | (vsw & 8)) * 8;
                __builtin_amdgcn_global_load_lds(
                    (const __attribute__((address_space(1))) unsigned int*)
                        (vbase + (size_t)rv * T_SEQ + c0n + vc),
                    (__attribute__((address_space(3))) unsigned int*)
                        (&Vsw[nb][(wave * 4 + i) * 512]),
                    16, 0, 0);
            }
        }

        const int cb = tile & 1;
#pragma unroll
        for (int half = 0; half < 2; ++half) {
            // S^T = K * Q^T (A=K m=kv, B=Q n=q), q-subtiles share K-frags
            f32x4 S[2][4];
#pragma unroll
            for (int qs = 0; qs < 2; ++qs)
#pragma unroll
                for (int nf = 0; nf < 4; ++nf) S[qs][nf] = (f32x4){0.f, 0.f, 0.f, 0.f};
#pragma unroll
            for (int ks = 0; ks < 2; ++ks) {
                const int ch = ks * 4 + quad;
#pragma unroll
                for (int nf = 0; nf < 4; ++nf) {
                    const int row = half * 64 + nf * 16 + l15;   // kv
                    const bf16x8 kf =
                        *(const bf16x8*)&Ksw[cb][row * 64 + ((ch ^ swz) * 8)];
                    S[0][nf] = __builtin_amdgcn_mfma_f32_16x16x32_bf16(
                        kf, qa[0][ks], S[0][nf], 0, 0, 0);
                    S[1][nf] = __builtin_amdgcn_mfma_f32_16x16x32_bf16(
                        kf, qa[1][ks], S[1][nf], 0, 0, 0);
                }
            }

            // exp -> paired P frags -> PV + L, all full-rate 16x16x32
#pragma unroll
            for (int gl = 0; gl < 2; ++gl) {
                bf16x8 pf[2];
#pragma unroll
                for (int qs = 0; qs < 2; ++qs) {
                    union { uint4 u; bf16x8 v; } cv;
                    const f32x4 s0 = S[qs][2 * gl];
                    const f32x4 s1 = S[qs][2 * gl + 1];
                    cv.u.x = pack_bf16x2(__builtin_amdgcn_exp2f(s0[0]),
                                         __builtin_amdgcn_exp2f(s0[1]));
                    cv.u.y = pack_bf16x2(__builtin_amdgcn_exp2f(s0[2]),
                                         __builtin_amdgcn_exp2f(s0[3]));
                    cv.u.z = pack_bf16x2(__builtin_amdgcn_exp2f(s1[0]),
                                         __builtin_amdgcn_exp2f(s1[1]));
                    cv.u.w = pack_bf16x2(__builtin_amdgcn_exp2f(s1[2]),
                                         __builtin_amdgcn_exp2f(s1[3]));
                    pf[qs] = cv.v;
                }
                const int g = half * 2 + gl;          // 32-kv group in tile
                const int c = g * 4 + quad;           // Vsw chunk index
                const int vo = (((c & 7) ^ swz) | (c & 8)) * 8;
#pragma unroll
                for (int nd = 0; nd < 4; ++nd) {
                    const bf16x8 vb =
                        *(const bf16x8*)&Vsw[cb][(nd * 16 + l15) * 128 + vo];
                    O[0][nd] = __builtin_amdgcn_mfma_f32_16x16x32_bf16(
                        pf[0], vb, O[0][nd], 0, 0, 0);
                    O[1][nd] = __builtin_amdgcn_mfma_f32_16x16x32_bf16(
                        pf[1], vb, O[1][nd], 0, 0, 0);
                }
                Lacc[0] = __builtin_amdgcn_mfma_f32_16x16x32_bf16(
                    pf[0], ones8, Lacc[0], 0, 0, 0);
                Lacc[1] = __builtin_amdgcn_mfma_f32_16x16x32_bf16(
                    pf[1], ones8, Lacc[1], 0, 0, 0);
            }
        }
    }

    // epilogue: rows q = q0 + wave*32 + qs*16 + quad*4 + r; cols h*64+nd*16+l15
#pragma unroll
    for (int qs = 0; qs < 2; ++qs)
#pragma unroll
        for (int r = 0; r < 4; ++r) {
            const float invl = 1.0f / Lacc[qs][r];
            const size_t rowbase =
                ((size_t)(b * T_SEQ) + q0 + wave * 32 + qs * 16 + quad * 4 + r)
                * D_MODEL + h * DK + l15;
#pragma unroll
            for (int nd = 0; nd < 4; ++nd) {
                const float v = O[qs][nd][r] * invl;
                const unsigned short hh = f32_to_bf16(v);
                ohi[rowbase + nd * 16] = hh;
                olo[rowbase + nd * 16] = f32_to_bf16(v - bf16_to_f32(hh));
            }
        }
}

// ---------------------------------------------------------------------------
extern "C" void kernel_launch(void* const* d_in, const int* in_sizes, int n_in,
                              void* d_out, int out_size, void* d_ws, size_t ws_size,
                              hipStream_t stream)
{
    const float* x      = (const float*)d_in[0];
    const float* W_qkv  = (const float*)d_in[1];
    const float* W_proj = (const float*)d_in[2];
    float* out = (float*)d_out;

    const size_t XN = (size_t)M_ROWS * D_MODEL;        // 8.4M
    const size_t WQ = (size_t)3 * D_MODEL * D_MODEL;   // 3.1M
    const size_t WP = (size_t)D_MODEL * D_MODEL;       // 1.0M
    unsigned short* xb   = (unsigned short*)d_ws;
    unsigned short* wqb  = xb + XN;
    unsigned short* wph  = wqb + WQ;
    unsigned short* wpl  = wph + WP;
    unsigned short* qkvb = wpl + WP;
    unsigned short* vtb  = qkvb + (size_t)M_ROWS * 3 * D_MODEL;
    unsigned short* alo  = vtb + (size_t)B_SZ * N_HEADS * DK * T_SEQ;
    unsigned short* ahi  = xb;   // overlay (x plane dead after QKV GEMM)

    dim3 blk(256);
    cast_bf16<<<512, blk, 0, stream>>>(x, xb, (int)XN, 0, 1.0f);
    cast_bf16<<<256, blk, 0, stream>>>(W_qkv, wqb, (int)WQ,
                                       D_MODEL * D_MODEL, QK_SCALE_LOG2);
    split_bf16<<<128, blk, 0, stream>>>(W_proj, wph, wpl, (int)WP);

    gemm_bf16_nt<<<dim3(3 * D_MODEL / 128, M_ROWS / 128), blk, 0, stream>>>(
        xb, wqb, qkvb, M_ROWS, 3 * D_MODEL, D_MODEL);

    prep_vt<<<dim3(T_SEQ / 256, N_HEADS, B_SZ), blk, 0, stream>>>(qkvb, vtb);
    attn_mfma<<<dim3(T_SEQ / 128, N_HEADS, B_SZ), blk, 0, stream>>>(
        qkvb, vtb, ahi, alo);

    gemm_split_nt<<<dim3(D_MODEL / 128, M_ROWS / 128), blk, 0, stream>>>(
        ahi, alo, wph, wpl, out, M_ROWS, D_MODEL, D_MODEL);
}

// Round 12
// 313.612 us; speedup vs baseline: 1.1140x; 1.0917x over previous
//
#include <hip/hip_runtime.h>
#include <hip/hip_bf16.h>

#define D_MODEL 1024
#define N_HEADS 16
#define DK 64
#define B_SZ 4
#define T_SEQ 2048
#define M_ROWS (B_SZ * T_SEQ)   // 8192
#define QK_SCALE_LOG2 0.18033688f   // 0.125 * log2(e), folded into W_qkv Q-rows

typedef short bf16x8 __attribute__((ext_vector_type(8)));
typedef float f32x4  __attribute__((ext_vector_type(4)));

__device__ inline unsigned short f32_to_bf16(float f) {
    union { float f; unsigned int u; } v; v.f = f;
    unsigned int r = v.u + 0x7fff + ((v.u >> 16) & 1);   // RNE
    return (unsigned short)(r >> 16);
}
__device__ inline unsigned int pack_bf16x2(float a, float b) {
    __hip_bfloat162 t = __float22bfloat162_rn(make_float2(a, b));
    union { __hip_bfloat162 v; unsigned int u; } c; c.v = t;
    return c.u;   // low 16 = a
}

// ---------------------------------------------------------------------------
// Cast fp32 -> bf16 (RNE); first nscaled elements multiplied by s.
// ---------------------------------------------------------------------------
__global__ __launch_bounds__(256) void cast_bf16(
    const float* __restrict__ src, unsigned short* __restrict__ dst,
    int n, int nscaled, float s)
{
    for (int i = (blockIdx.x * 256 + threadIdx.x) * 4; i < n;
         i += gridDim.x * 256 * 4) {
        float4 v = *(const float4*)(src + i);
        const float sc = (i < nscaled) ? s : 1.0f;
        ushort4 h;
        h.x = f32_to_bf16(v.x * sc); h.y = f32_to_bf16(v.y * sc);
        h.z = f32_to_bf16(v.z * sc); h.w = f32_to_bf16(v.w * sc);
        *(ushort4*)(dst + i) = h;
    }
}

// ---------------------------------------------------------------------------
// Plain bf16 NT GEMM, templated output (bf16 for qkv, fp32 for final out).
// Error: only input-rounding (2^-9 rel) — fine for both uses (see R12 notes).
// ---------------------------------------------------------------------------
template <typename OutT>
__global__ __launch_bounds__(256) void gemm_bf16_nt(
    const unsigned short* __restrict__ A, const unsigned short* __restrict__ B,
    OutT* __restrict__ C, int M, int N, int K)
{
    __shared__ __align__(16) unsigned short sA[128 * 32];
    __shared__ __align__(16) unsigned short sB[128 * 32];

    const int t    = threadIdx.x;
    const int wave = t >> 6;
    const int lane = t & 63;
    const int l15  = lane & 15;
    const int quad = lane >> 4;
    const int m0   = blockIdx.y * 128;
    const int n0   = blockIdx.x * 128;

    const unsigned short* gplane = (wave < 2) ? A : B;
    unsigned short* lplane = (wave < 2) ? sA : sB;
    const int row0 = ((wave < 2) ? m0 : n0) + (wave & 1) * 64;
    const int lds0 = (wave & 1) * 2048;
    const unsigned short* gbase =
        gplane + (size_t)(row0 + (lane >> 2)) * K + (lane & 3) * 8;

    f32x4 acc[4][4];
#pragma unroll
    for (int i = 0; i < 4; ++i)
#pragma unroll
        for (int j = 0; j < 4; ++j) acc[i][j] = (f32x4){0.f, 0.f, 0.f, 0.f};

    const int wr = (wave >> 1) * 64;
    const int wc = (wave & 1) * 64;

    for (int k0 = 0; k0 < K; k0 += 32) {
#pragma unroll
        for (int i = 0; i < 4; ++i) {
            __builtin_amdgcn_global_load_lds(
                (const __attribute__((address_space(1))) unsigned int*)
                    (gbase + k0 + (size_t)i * 16 * K),
                (__attribute__((address_space(3))) unsigned int*)
                    (lplane + lds0 + i * 512),
                16, 0, 0);
        }
        __syncthreads();

        bf16x8 a[4], b[4];
#pragma unroll
        for (int f = 0; f < 4; ++f) {
            a[f] = *(const bf16x8*)&sA[(wr + f * 16 + l15) * 32 + quad * 8];
            b[f] = *(const bf16x8*)&sB[(wc + f * 16 + l15) * 32 + quad * 8];
        }
#pragma unroll
        for (int mi = 0; mi < 4; ++mi)
#pragma unroll
            for (int ni = 0; ni < 4; ++ni)
                acc[mi][ni] = __builtin_amdgcn_mfma_f32_16x16x32_bf16(
                    a[mi], b[ni], acc[mi][ni], 0, 0, 0);
        __syncthreads();
    }

#pragma unroll
    for (int mi = 0; mi < 4; ++mi)
#pragma unroll
        for (int r = 0; r < 4; ++r) {
            OutT* crow =
                C + (size_t)(m0 + wr + mi * 16 + quad * 4 + r) * N + n0 + wc + l15;
#pragma unroll
            for (int ni = 0; ni < 4; ++ni) {
                if constexpr (sizeof(OutT) == 2)
                    crow[ni * 16] = (OutT)f32_to_bf16(acc[mi][ni][r]);
                else
                    crow[ni * 16] = (OutT)acc[mi][ni][r];
            }
        }
}

// ---------------------------------------------------------------------------
// Build V^T per (b,h) with PV kv-permutation baked in (unchanged):
// vt[b,h,dk,pos], pos = (kv&~31) | quad(kv)<<3 | s(kv)<<2 | r(kv).
// ---------------------------------------------------------------------------
__global__ __launch_bounds__(256) void prep_vt(
    const unsigned short* __restrict__ qkvb, unsigned short* __restrict__ vt)
{
    __shared__ unsigned short VT_s[64][264];
    const int t  = threadIdx.x;
    const int b  = blockIdx.z, h = blockIdx.y;
    const int t0 = blockIdx.x * 256;
    const unsigned short* vb = qkvb + (size_t)(b * T_SEQ) * (3 * D_MODEL)
                               + 2 * D_MODEL + h * DK;
#pragma unroll
    for (int it = 0; it < 16; ++it) {
        const int trow = (t >> 4) + it * 16;
        const int dk0  = (t & 15) * 4;
        ushort4 v = *(const ushort4*)(vb + (size_t)(t0 + trow) * (3 * D_MODEL) + dk0);
        VT_s[dk0 + 0][trow] = v.x; VT_s[dk0 + 1][trow] = v.y;
        VT_s[dk0 + 2][trow] = v.z; VT_s[dk0 + 3][trow] = v.w;
    }
    __syncthreads();
    const int row = t >> 2;
    const int c0w = (t & 3) * 64;
    unsigned short* dst = vt + ((size_t)(b * N_HEADS + h) * DK + row) * T_SEQ + t0 + c0w;
#pragma unroll
    for (int i = 0; i < 8; ++i) {
        const int lp8   = c0w + i * 8;
        const int sbase = (lp8 & ~31) + ((lp8 >> 3) & 3) * 4;
        ushort4 a  = *(const ushort4*)&VT_s[row][sbase];        // s=0
        ushort4 b4 = *(const ushort4*)&VT_s[row][sbase + 16];   // s=1
        union { ushort4 p[2]; uint4 v; } pk;
        pk.p[0] = a; pk.p[1] = b4;
        *(uint4*)(dst + i * 8) = pk.v;
    }
}

// ---------------------------------------------------------------------------
// MFMA flash attention (R11 structure: dbuf async staging, 1 barrier/tile,
// full-rate paired PV). R12: epilogue writes a single bf16 plane.
// ---------------------------------------------------------------------------
__global__ __launch_bounds__(256) void attn_mfma(
    const unsigned short* __restrict__ qkvb,   // [B,T,3D] bf16 (Q pre-scaled)
    const unsigned short* __restrict__ vt,     // [B,H,DK,T] bf16, kv-permuted
    unsigned short* __restrict__ ob)           // [B,T,D] bf16
{
    __shared__ __align__(16) unsigned short Ksw[2][128 * 64];  // [kv][dk] swizzled
    __shared__ __align__(16) unsigned short Vsw[2][64 * 128];  // [dk][pos] swizzled

    const int t    = threadIdx.x;
    const int wave = t >> 6;
    const int lane = t & 63;
    const int l15  = t & 15;
    const int quad = lane >> 4;
    const int swz  = l15 & 7;

    const int b  = blockIdx.z;
    const int h  = blockIdx.y;
    const int q0 = blockIdx.x * 128;

    // Q fragments (loop-invariant): 2 q-subtiles x 2 dk-chunks
    bf16x8 qa[2][2];
#pragma unroll
    for (int qs = 0; qs < 2; ++qs) {
        const unsigned short* qrow =
            qkvb + ((size_t)(b * T_SEQ) + q0 + wave * 32 + qs * 16 + l15)
                   * (3 * D_MODEL) + h * DK;
        qa[qs][0] = *(const bf16x8*)(qrow + quad * 8);
        qa[qs][1] = *(const bf16x8*)(qrow + 32 + quad * 8);
    }

    f32x4 O[2][4], Lacc[2];
#pragma unroll
    for (int qs = 0; qs < 2; ++qs) {
        Lacc[qs] = (f32x4){0.f, 0.f, 0.f, 0.f};
#pragma unroll
        for (int nd = 0; nd < 4; ++nd) O[qs][nd] = (f32x4){0.f, 0.f, 0.f, 0.f};
    }

    const short one_bf = (short)0x3F80;
    const bf16x8 ones8 = {one_bf, one_bf, one_bf, one_bf,
                          one_bf, one_bf, one_bf, one_bf};

    const unsigned short* kbase =
        qkvb + (size_t)(b * T_SEQ) * (3 * D_MODEL) + D_MODEL + h * DK;
    const unsigned short* vbase = vt + (size_t)(b * N_HEADS + h) * DK * T_SEQ;

    // source-side swizzle (tile-invariant pieces)
    const int krl  = wave * 32 + (lane >> 3);
    const int kcol = ((lane & 7) ^ (lane >> 3)) * 8;
    const int vrl = wave * 16 + (lane >> 4);
    const int vsw = lane & 15;

    // prologue: issue tile 0 loads into buffer 0
#pragma unroll
    for (int i = 0; i < 4; ++i) {
        const int rk = krl + i * 8;
        __builtin_amdgcn_global_load_lds(
            (const __attribute__((address_space(1))) unsigned int*)
                (kbase + (size_t)rk * (3 * D_MODEL) + kcol),
            (__attribute__((address_space(3))) unsigned int*)
                (&Ksw[0][(wave * 4 + i) * 512]),
            16, 0, 0);
        const int rv = vrl + i * 4;
        const int vc = (((vsw & 7) ^ (rv & 7)) | (vsw & 8)) * 8;
        __builtin_amdgcn_global_load_lds(
            (const __attribute__((address_space(1))) unsigned int*)
                (vbase + (size_t)rv * T_SEQ + vc),
            (__attribute__((address_space(3))) unsigned int*)
                (&Vsw[0][(wave * 4 + i) * 512]),
            16, 0, 0);
    }

    const int NT = T_SEQ / 128;
    for (int tile = 0; tile < NT; ++tile) {
        __syncthreads();   // drains this tile's loads (issued one iter ago)

        if (tile + 1 < NT) {
            const int c0n = (tile + 1) * 128;
            const int nb  = (tile + 1) & 1;
#pragma unroll
            for (int i = 0; i < 4; ++i) {
                const int rk = krl + i * 8;
                __builtin_amdgcn_global_load_lds(
                    (const __attribute__((address_space(1))) unsigned int*)
                        (kbase + (size_t)(c0n + rk) * (3 * D_MODEL) + kcol),
                    (__attribute__((address_space(3))) unsigned int*)
                        (&Ksw[nb][(wave * 4 + i) * 512]),
                    16, 0, 0);
                const int rv = vrl + i * 4;
                const int vc = (((vsw & 7) ^ (rv & 7)) | (vsw & 8)) * 8;
                __builtin_amdgcn_global_load_lds(
                    (const __attribute__((address_space(1))) unsigned int*)
                        (vbase + (size_t)rv * T_SEQ + c0n + vc),
                    (__attribute__((address_space(3))) unsigned int*)
                        (&Vsw[nb][(wave * 4 + i) * 512]),
                    16, 0, 0);
            }
        }

        const int cb = tile & 1;
#pragma unroll
        for (int half = 0; half < 2; ++half) {
            f32x4 S[2][4];
#pragma unroll
            for (int qs = 0; qs < 2; ++qs)
#pragma unroll
                for (int nf = 0; nf < 4; ++nf) S[qs][nf] = (f32x4){0.f, 0.f, 0.f, 0.f};
#pragma unroll
            for (int ks = 0; ks < 2; ++ks) {
                const int ch = ks * 4 + quad;
#pragma unroll
                for (int nf = 0; nf < 4; ++nf) {
                    const int row = half * 64 + nf * 16 + l15;   // kv
                    const bf16x8 kf =
                        *(const bf16x8*)&Ksw[cb][row * 64 + ((ch ^ swz) * 8)];
                    S[0][nf] = __builtin_amdgcn_mfma_f32_16x16x32_bf16(
                        kf, qa[0][ks], S[0][nf], 0, 0, 0);
                    S[1][nf] = __builtin_amdgcn_mfma_f32_16x16x32_bf16(
                        kf, qa[1][ks], S[1][nf], 0, 0, 0);
                }
            }

#pragma unroll
            for (int gl = 0; gl < 2; ++gl) {
                bf16x8 pf[2];
#pragma unroll
                for (int qs = 0; qs < 2; ++qs) {
                    union { uint4 u; bf16x8 v; } cv;
                    const f32x4 s0 = S[qs][2 * gl];
                    const f32x4 s1 = S[qs][2 * gl + 1];
                    cv.u.x = pack_bf16x2(__builtin_amdgcn_exp2f(s0[0]),
                                         __builtin_amdgcn_exp2f(s0[1]));
                    cv.u.y = pack_bf16x2(__builtin_amdgcn_exp2f(s0[2]),
                                         __builtin_amdgcn_exp2f(s0[3]));
                    cv.u.z = pack_bf16x2(__builtin_amdgcn_exp2f(s1[0]),
                                         __builtin_amdgcn_exp2f(s1[1]));
                    cv.u.w = pack_bf16x2(__builtin_amdgcn_exp2f(s1[2]),
                                         __builtin_amdgcn_exp2f(s1[3]));
                    pf[qs] = cv.v;
                }
                const int g = half * 2 + gl;
                const int c = g * 4 + quad;
                const int vo = (((c & 7) ^ swz) | (c & 8)) * 8;
#pragma unroll
                for (int nd = 0; nd < 4; ++nd) {
                    const bf16x8 vb =
                        *(const bf16x8*)&Vsw[cb][(nd * 16 + l15) * 128 + vo];
                    O[0][nd] = __builtin_amdgcn_mfma_f32_16x16x32_bf16(
                        pf[0], vb, O[0][nd], 0, 0, 0);
                    O[1][nd] = __builtin_amdgcn_mfma_f32_16x16x32_bf16(
                        pf[1], vb, O[1][nd], 0, 0, 0);
                }
                Lacc[0] = __builtin_amdgcn_mfma_f32_16x16x32_bf16(
                    pf[0], ones8, Lacc[0], 0, 0, 0);
                Lacc[1] = __builtin_amdgcn_mfma_f32_16x16x32_bf16(
                    pf[1], ones8, Lacc[1], 0, 0, 0);
            }
        }
    }

    // epilogue: single bf16 plane
#pragma unroll
    for (int qs = 0; qs < 2; ++qs)
#pragma unroll
        for (int r = 0; r < 4; ++r) {
            const float invl = 1.0f / Lacc[qs][r];
            const size_t rowbase =
                ((size_t)(b * T_SEQ) + q0 + wave * 32 + qs * 16 + quad * 4 + r)
                * D_MODEL + h * DK + l15;
#pragma unroll
            for (int nd = 0; nd < 4; ++nd)
                ob[rowbase + nd * 16] = f32_to_bf16(O[qs][nd][r] * invl);
        }
}

// ---------------------------------------------------------------------------
extern "C" void kernel_launch(void* const* d_in, const int* in_sizes, int n_in,
                              void* d_out, int out_size, void* d_ws, size_t ws_size,
                              hipStream_t stream)
{
    const float* x      = (const float*)d_in[0];
    const float* W_qkv  = (const float*)d_in[1];
    const float* W_proj = (const float*)d_in[2];
    float* out = (float*)d_out;

    const size_t XN = (size_t)M_ROWS * D_MODEL;        // 8.4M
    const size_t WQ = (size_t)3 * D_MODEL * D_MODEL;   // 3.1M
    const size_t WP = (size_t)D_MODEL * D_MODEL;       // 1.0M
    unsigned short* xb   = (unsigned short*)d_ws;
    unsigned short* wqb  = xb + XN;
    unsigned short* wpb  = wqb + WQ;
    unsigned short* qkvb = wpb + WP;
    unsigned short* vtb  = qkvb + (size_t)M_ROWS * 3 * D_MODEL;
    unsigned short* ab   = xb;   // overlay (x plane dead after QKV GEMM)

    dim3 blk(256);
    cast_bf16<<<512, blk, 0, stream>>>(x, xb, (int)XN, 0, 1.0f);
    cast_bf16<<<256, blk, 0, stream>>>(W_qkv, wqb, (int)WQ,
                                       D_MODEL * D_MODEL, QK_SCALE_LOG2);
    cast_bf16<<<128, blk, 0, stream>>>(W_proj, wpb, (int)WP, 0, 1.0f);

    gemm_bf16_nt<unsigned short>
        <<<dim3(3 * D_MODEL / 128, M_ROWS / 128), blk, 0, stream>>>(
        xb, wqb, qkvb, M_ROWS, 3 * D_MODEL, D_MODEL);

    prep_vt<<<dim3(T_SEQ / 256, N_HEADS, B_SZ), blk, 0, stream>>>(qkvb, vtb);
    attn_mfma<<<dim3(T_SEQ / 128, N_HEADS, B_SZ), blk, 0, stream>>>(
        qkvb, vtb, ab);

    gemm_bf16_nt<float>
        <<<dim3(D_MODEL / 128, M_ROWS / 128), blk, 0, stream>>>(
        ab, wpb, out, M_ROWS, D_MODEL, D_MODEL);
}